// Round 15
// baseline (1029.922 us; speedup 1.0000x reference)
//
#include <hip/hip_runtime.h>
#include <hip/hip_bf16.h>

// Fused transformer block as a 3-kernel pipeline:
//   prep_w     : f32 weights -> bf16 transposed in ws (1.5 MB only).
//   attnproj_k : LN1 -> per-head (QKV -> causal softmax -> PV -> proj-accum
//                in regs) -> x2 = x + sa + bproj -> f32 in d_out. Proven R9.
//   mlp_k      : 16 waves, swapped ops, 2-way M x 8-way N split: wave owns
//                32 out-cols x 64 rows, so each LDS B-fragment read feeds
//                2 MFMAs -> LDS read volume halves (R14 analysis: mlp was
//                LDS-read-BW-bound at 1 read/MFMA, ~218us of LDS pipe).
//                Cost: 2x weight L2 duplication (~116us, overlapped pipe).
// R12 lesson: live set must not grow past cap (spills). acc = 64 regs here,
// est ~95 total < 128 cap of (1024,1). R10 lesson: no new barriers (kept 9).
// ws layout (bf16/ushort): [0,65536) WqT[h][d][c]; [65536,131072) WkT;
// [131072,196608) WvT; [196608,262144) WprojT[n][c]; [262144,524288) W1T[n][c];
// [524288,786432) W2T[n][k].  Requires ws_size >= 1572864 bytes only.

typedef float v4f __attribute__((ext_vector_type(4)));
typedef int   v4i __attribute__((ext_vector_type(4)));
typedef float f4v __attribute__((ext_vector_type(4)));
typedef unsigned long long u64;

#define DEV static __device__ __forceinline__

DEV unsigned short f2bf(float f){
  return __builtin_bit_cast(unsigned short, __float2bfloat16(f));
}

// lgkm-only workgroup barrier: orders LDS traffic, leaves global loads in
// flight. Safe because all cross-wave data in these kernels flows via LDS.
DEV void bar(){
  asm volatile("s_waitcnt lgkmcnt(0)\n\ts_barrier" ::: "memory");
}

// bf16 MFMA via inline asm (layout-safe: consistent per-lane contiguous-8 K).
DEV v4f mfma16(v4i a, v4i b, v4f c){
  asm("v_mfma_f32_16x16x32_bf16 %0, %1, %2, %0" : "+v"(c) : "v"(a), "v"(b));
  return c;
}
DEV v4f accfence(v4f c){
  asm("s_nop 7\n\ts_nop 3" : "+v"(c));
  return c;
}

// Swizzled LDS byte offsets (XOR row bits into 16B-granule bits).
DEV int hoff(int r, int c){ return r*512 + ((c*2) ^ ((r & 7) << 4)); }  // [*][256] bf16
DEV int koff(int r, int c){ return r*128 + ((c*2) ^ ((r & 7) << 4)); }  // [*][64]  bf16

DEV u64 pack4(v4f v){
  return (u64)f2bf(v[0]) | ((u64)f2bf(v[1]) << 16)
       | ((u64)f2bf(v[2]) << 32) | ((u64)f2bf(v[3]) << 48);
}

DEV float rsum64(float v){
  #pragma unroll
  for (int k = 1; k < 64; k <<= 1) v += __shfl_xor(v, k);
  return v;
}
DEV float rsum16(float v){
  #pragma unroll
  for (int k = 1; k < 16; k <<= 1) v += __shfl_xor(v, k);
  return v;
}
DEV float rmax16(float v){
  #pragma unroll
  for (int k = 1; k < 16; k <<= 1) v = fmaxf(v, __shfl_xor(v, k));
  return v;
}

__global__ void prep_w(const float* __restrict__ Wq, const float* __restrict__ Wk,
                       const float* __restrict__ Wv, const float* __restrict__ Wp,
                       const float* __restrict__ W1, const float* __restrict__ W2,
                       unsigned short* __restrict__ ws){
  int t = blockIdx.x * 256 + threadIdx.x;   // grid covers exactly 786432
  float v;
  if (t < 196608){
    int seg = t >> 16, r = t & 65535;
    int c = r & 255, d = (r >> 8) & 63, h = r >> 14;
    const float* W = (seg == 0) ? Wq : ((seg == 1) ? Wk : Wv);
    v = W[h*16384 + c*64 + d];
  } else if (t < 262144){
    int r = t - 196608; int n = r >> 8, c = r & 255;
    v = Wp[c*256 + n];
  } else if (t < 524288){
    int r = t - 262144; int n = r >> 8, c = r & 255;
    v = W1[c*1024 + n];
  } else {
    int r = t - 524288; int n = r >> 10, k = r & 1023;
    v = W2[k*256 + n];
  }
  ws[t] = f2bf(v);
}

// ---------------- attnproj_k: LN1 + attention + proj + residual --------------
// One 4-wave block per batch element; proven numerics, unchanged from R9.
__global__ __launch_bounds__(256, 2) void attnproj_k(
    const float* __restrict__ x,
    const float* __restrict__ ln1g, const float* __restrict__ ln1b,
    const unsigned short* __restrict__ wqT,
    const unsigned short* __restrict__ wkT,
    const unsigned short* __restrict__ wvT,
    const unsigned short* __restrict__ wpT,
    const float* __restrict__ bpj,
    float* __restrict__ outp)
{
  __shared__ char smb[65536] __attribute__((aligned(16)));
  char* sm = smb;
  const int HLS = 0, QLS = 32768, KLS = 40960, VTLS = 49152, PATLS = 57344;

  const int b = blockIdx.x;
  const float* __restrict__ xb = x + (size_t)b * 16384;
  float* __restrict__ ob = outp + (size_t)b * 16384;
  const int tid = threadIdx.x;
  const int w = tid >> 6, l = tid & 63, m = l & 15, g = l >> 4;
  const v4f zf = {0.f, 0.f, 0.f, 0.f};

  // Phase A: LN1 -> h (bf16, LDS), 16 rows/wave
  {
    f4v lg = *(const f4v*)(ln1g + 4*l);
    f4v lb = *(const f4v*)(ln1b + 4*l);
    #pragma unroll
    for (int rr = 0; rr < 16; ++rr){
      int r = w*16 + rr;
      f4v xv = *(const f4v*)(xb + r*256 + 4*l);
      float s = xv[0]+xv[1]+xv[2]+xv[3];
      float q = xv[0]*xv[0]+xv[1]*xv[1]+xv[2]*xv[2]+xv[3]*xv[3];
      s = rsum64(s); q = rsum64(q);
      float mu = s * (1.f/256.f);
      float rs = rsqrtf(q * (1.f/256.f) - mu*mu + 1e-6f);
      u64 pk = 0;
      #pragma unroll
      for (int j = 0; j < 4; ++j){
        float hv = (xv[j] - mu) * rs * lg[j] + lb[j];
        pk |= (u64)f2bf(hv) << (16*j);
      }
      *(u64*)(sm + HLS + hoff(r, 4*l)) = pk;
    }
  }
  bar();

  // Phase B: attention; sa accumulated in regs
  v4f sa[4][4];
  #pragma unroll
  for (int i = 0; i < 4; ++i){
    #pragma unroll
    for (int j = 0; j < 4; ++j) sa[i][j] = zf;
  }

  #pragma unroll 1
  for (int hh = 0; hh < 4; ++hh){
    // QKV: wave w owns cols w*16..w*16+15 of q,k,v (shared A-fragments)
    {
      const unsigned short* bq = wqT + hh*16384 + (w*16 + m)*256;
      const unsigned short* bk = wkT + hh*16384 + (w*16 + m)*256;
      const unsigned short* bv = wvT + hh*16384 + (w*16 + m)*256;
      v4f qa[4] = {zf,zf,zf,zf}, ka[4] = {zf,zf,zf,zf}, va[4] = {zf,zf,zf,zf};
      #pragma unroll
      for (int ks = 0; ks < 8; ++ks){
        int k0 = ks*32 + 8*g;
        v4i bq4 = *(const v4i*)(bq + k0);
        v4i bk4 = *(const v4i*)(bk + k0);
        v4i bv4 = *(const v4i*)(bv + k0);
        #pragma unroll
        for (int rt = 0; rt < 4; ++rt){
          v4i af = *(const v4i*)(sm + HLS + hoff(rt*16 + m, k0));
          qa[rt] = mfma16(af, bq4, qa[rt]);
          ka[rt] = mfma16(af, bk4, ka[rt]);
          va[rt] = mfma16(af, bv4, va[rt]);
        }
      }
      #pragma unroll
      for (int rt = 0; rt < 4; ++rt){
        qa[rt] = accfence(qa[rt]); ka[rt] = accfence(ka[rt]); va[rt] = accfence(va[rt]);
        #pragma unroll
        for (int j = 0; j < 4; ++j){
          *(unsigned short*)(sm + QLS + koff(rt*16 + 4*g + j, w*16 + m)) = f2bf(qa[rt][j]);
          *(unsigned short*)(sm + KLS + koff(rt*16 + 4*g + j, w*16 + m)) = f2bf(ka[rt][j]);
        }
        *(u64*)(sm + VTLS + koff(w*16 + m, rt*16 + 4*g)) = pack4(va[rt]);  // V^T
      }
    }
    bar();   // bar1: q,k,v^T ready; prev-head PATLS readers done

    // S = Q K^T (stripe rows w*16..+15) -> softmax -> P -> PV -> own PATLS
    {
      v4f s4[4] = {zf,zf,zf,zf};
      #pragma unroll
      for (int ks = 0; ks < 2; ++ks){
        int k0 = ks*32 + 8*g;
        v4i qf = *(const v4i*)(sm + QLS + koff(w*16 + m, k0));
        #pragma unroll
        for (int nt = 0; nt < 4; ++nt){
          v4i kf = *(const v4i*)(sm + KLS + koff(nt*16 + m, k0));
          s4[nt] = mfma16(qf, kf, s4[nt]);
        }
      }
      #pragma unroll
      for (int nt = 0; nt < 4; ++nt) s4[nt] = accfence(s4[nt]);
      float mx[4] = {-3e38f, -3e38f, -3e38f, -3e38f};
      #pragma unroll
      for (int nt = 0; nt < 4; ++nt){
        #pragma unroll
        for (int j = 0; j < 4; ++j){
          int t = w*16 + 4*g + j, ss = nt*16 + m;
          float z = s4[nt][j] * 0.125f;
          z = (ss <= t) ? z : -1e30f;
          s4[nt][j] = z;
          mx[j] = fmaxf(mx[j], z);
        }
      }
      #pragma unroll
      for (int j = 0; j < 4; ++j) mx[j] = rmax16(mx[j]);
      float sum[4] = {0.f, 0.f, 0.f, 0.f};
      #pragma unroll
      for (int nt = 0; nt < 4; ++nt){
        #pragma unroll
        for (int j = 0; j < 4; ++j){
          float p = __expf(s4[nt][j] - mx[j]);
          s4[nt][j] = p;
          sum[j] += p;
        }
      }
      #pragma unroll
      for (int j = 0; j < 4; ++j) sum[j] = 1.f / rsum16(sum[j]);
      #pragma unroll
      for (int nt = 0; nt < 4; ++nt){
        #pragma unroll
        for (int j = 0; j < 4; ++j)
          *(unsigned short*)(sm + PATLS + w*2048 + koff(4*g + j, nt*16 + m)) =
              f2bf(s4[nt][j] * sum[j]);
      }
      v4f av[4] = {zf,zf,zf,zf};
      #pragma unroll
      for (int ks = 0; ks < 2; ++ks){
        int k0 = ks*32 + 8*g;
        v4i pf = *(const v4i*)(sm + PATLS + w*2048 + koff(m, k0));
        #pragma unroll
        for (int nt = 0; nt < 4; ++nt){
          v4i vf = *(const v4i*)(sm + VTLS + koff(nt*16 + m, k0));
          av[nt] = mfma16(pf, vf, av[nt]);
        }
      }
      #pragma unroll
      for (int nt = 0; nt < 4; ++nt) av[nt] = accfence(av[nt]);
      #pragma unroll
      for (int nt = 0; nt < 4; ++nt){
        #pragma unroll
        for (int j = 0; j < 4; ++j)
          *(unsigned short*)(sm + PATLS + w*2048 + koff(4*g + j, nt*16 + m)) =
              f2bf(av[nt][j]);
      }
    }
    bar();   // bar2: att stripes ready

    // proj: sa += att_head @ Wproj[64*hh:, :]; wave w owns cols w*64..w*64+63
    #pragma unroll
    for (int ks = 0; ks < 2; ++ks){
      int k0 = ks*32 + 8*g;
      v4i af2[4];
      #pragma unroll
      for (int rt = 0; rt < 4; ++rt)
        af2[rt] = *(const v4i*)(sm + PATLS + rt*2048 + koff(m, k0));
      #pragma unroll
      for (int nt = 0; nt < 4; ++nt){
        v4i bp = *(const v4i*)(wpT + (w*64 + nt*16 + m)*256 + hh*64 + k0);
        #pragma unroll
        for (int rt = 0; rt < 4; ++rt) sa[rt][nt] = mfma16(af2[rt], bp, sa[rt][nt]);
      }
    }
    // no trailing barrier: PATLS next written after next bar1.
  }

  // Phase C residual: x2 = x + sa + bproj -> f32 in d_out
  {
    #pragma unroll
    for (int i = 0; i < 4; ++i){
      #pragma unroll
      for (int j = 0; j < 4; ++j) sa[i][j] = accfence(sa[i][j]);
    }
    float bp4[4];
    #pragma unroll
    for (int nt = 0; nt < 4; ++nt) bp4[nt] = bpj[w*64 + nt*16 + m];
    #pragma unroll
    for (int rt = 0; rt < 4; ++rt){
      #pragma unroll
      for (int j = 0; j < 4; ++j){
        int row = rt*16 + 4*g + j;
        #pragma unroll
        for (int nt = 0; nt < 4; ++nt){
          int col = w*64 + nt*16 + m;
          ob[row*256 + col] = xb[row*256 + col] + sa[rt][nt][j] + bp4[nt];
        }
      }
    }
  }
}

// ---------------- mlp_k: 2 batch/block (M=128), 16 waves, 2M x 8N split ------
// LDS 128KB dynamic: h2 [128][256] bf16 @0 | act chunk [128][256] bf16 @64K.
// Wave (mq,nq) = (w>>3, w&7): rows mq*64..+63 (4 tiles), cols nq*32..+31
// (2 frags). Each LDS B-read feeds 2 MFMAs. 4 chunks x (GEMM1, bar, GEMM2,
// bar) = 9 lgkm barriers.
#define MLP_LDS 131072
__global__ __launch_bounds__(1024, 1) void mlp_k(
    const float* __restrict__ ln2g, const float* __restrict__ ln2b,
    const unsigned short* __restrict__ w1T,
    const float* __restrict__ b1,
    const unsigned short* __restrict__ w2T,
    const float* __restrict__ b2,
    float* __restrict__ outp)
{
  extern __shared__ char sm[];
  const int HLS = 0, ACT = 65536;
  const int bb = blockIdx.x;               // 2-batch slab
  float* __restrict__ ob = outp + (size_t)bb * 32768;
  const int tid = threadIdx.x;
  const int w = tid >> 6, l = tid & 63, m = l & 15, g = l >> 4;
  const int mq = w >> 3, nq = w & 7;
  const v4f zf = {0.f, 0.f, 0.f, 0.f};

  // LN2 from x2 (f32 in d_out) -> h2 (bf16, LDS); 16 waves x 8 rows = 128
  {
    f4v lg = *(const f4v*)(ln2g + 4*l);
    f4v lb = *(const f4v*)(ln2b + 4*l);
    #pragma unroll
    for (int rr = 0; rr < 8; ++rr){
      int r = w*8 + rr;
      f4v xv = *(const f4v*)(ob + r*256 + 4*l);
      float s = xv[0]+xv[1]+xv[2]+xv[3];
      float q = xv[0]*xv[0]+xv[1]*xv[1]+xv[2]*xv[2]+xv[3]*xv[3];
      s = rsum64(s); q = rsum64(q);
      float mu = s * (1.f/256.f);
      float rs = rsqrtf(q * (1.f/256.f) - mu*mu + 1e-6f);
      u64 pk = 0;
      #pragma unroll
      for (int j = 0; j < 4; ++j){
        float hv = (xv[j] - mu) * rs * lg[j] + lb[j];
        pk |= (u64)f2bf(hv) << (16*j);
      }
      *(u64*)(sm + HLS + hoff(r, 4*l)) = pk;
    }
  }
  bar();

  v4f ff[2][4];                            // [out-col frag][row tile]
  #pragma unroll
  for (int i = 0; i < 2; ++i)
    #pragma unroll
    for (int j = 0; j < 4; ++j) ff[i][j] = zf;

  #pragma unroll 1
  for (int ch = 0; ch < 4; ++ch){
    // GEMM1 (A=W1T rows = out-cols, B=h2 rows): a1[oc][rt]
    v4f a1[2][4];
    #pragma unroll
    for (int i = 0; i < 2; ++i)
      #pragma unroll
      for (int j = 0; j < 4; ++j) a1[i][j] = zf;
    const unsigned short* w1a = w1T + (ch*256 + nq*32 +      m)*256;
    const unsigned short* w1b = w1T + (ch*256 + nq*32 + 16 + m)*256;
    #pragma unroll
    for (int ks = 0; ks < 8; ++ks){
      int k0 = ks*32 + 8*g;
      v4i aw0 = *(const v4i*)(w1a + k0);
      v4i aw1 = *(const v4i*)(w1b + k0);
      #pragma unroll
      for (int rt = 0; rt < 4; ++rt){
        v4i bh = *(const v4i*)(sm + HLS + hoff(mq*64 + rt*16 + m, k0));
        a1[0][rt] = mfma16(aw0, bh, a1[0][rt]);
        a1[1][rt] = mfma16(aw1, bh, a1[1][rt]);
      }
    }
    // bias + relu + packed act store: act[mq*64+rt*16+m][nq*32+oc*16+4g+j]
    f4v b1f[2];
    #pragma unroll
    for (int oc = 0; oc < 2; ++oc)
      b1f[oc] = *(const f4v*)(b1 + ch*256 + nq*32 + oc*16 + 4*g);
    #pragma unroll
    for (int i = 0; i < 2; ++i)
      #pragma unroll
      for (int j = 0; j < 4; ++j) a1[i][j] = accfence(a1[i][j]);
    #pragma unroll
    for (int oc = 0; oc < 2; ++oc){
      #pragma unroll
      for (int rt = 0; rt < 4; ++rt){
        v4f v;
        #pragma unroll
        for (int j = 0; j < 4; ++j) v[j] = fmaxf(a1[oc][rt][j] + b1f[oc][j], 0.f);
        *(u64*)(sm + ACT + hoff(mq*64 + rt*16 + m, nq*32 + oc*16 + 4*g)) = pack4(v);
      }
    }
    bar();   // act chunk ready

    // GEMM2 (A=W2T rows = final out-cols, B=act rows): ff[oc][rt]
    const unsigned short* w2a = w2T + (nq*32 +      m)*1024 + ch*256;
    const unsigned short* w2b = w2T + (nq*32 + 16 + m)*1024 + ch*256;
    #pragma unroll
    for (int ks = 0; ks < 8; ++ks){
      int k0 = ks*32 + 8*g;
      v4i aw0 = *(const v4i*)(w2a + k0);
      v4i aw1 = *(const v4i*)(w2b + k0);
      #pragma unroll
      for (int rt = 0; rt < 4; ++rt){
        v4i bact = *(const v4i*)(sm + ACT + hoff(mq*64 + rt*16 + m, k0));
        ff[0][rt] = mfma16(aw0, bact, ff[0][rt]);
        ff[1][rt] = mfma16(aw1, bact, ff[1][rt]);
      }
    }
    bar();   // protect act before next chunk's GEMM1 overwrite
  }

  // Final: out = x2 + ff + b2, float4 RMW (4 consecutive cols per lane)
  {
    f4v b2f[2];
    #pragma unroll
    for (int oc = 0; oc < 2; ++oc)
      b2f[oc] = *(const f4v*)(b2 + nq*32 + oc*16 + 4*g);
    #pragma unroll
    for (int i = 0; i < 2; ++i)
      #pragma unroll
      for (int j = 0; j < 4; ++j) ff[i][j] = accfence(ff[i][j]);
    #pragma unroll
    for (int oc = 0; oc < 2; ++oc){
      #pragma unroll
      for (int rt = 0; rt < 4; ++rt){
        int row = mq*64 + rt*16 + m;
        f4v* p = (f4v*)(ob + row*256 + nq*32 + oc*16 + 4*g);
        f4v v = *p;
        #pragma unroll
        for (int j = 0; j < 4; ++j) v[j] += ff[oc][rt][j] + b2f[oc][j];
        *p = v;
      }
    }
  }
}

extern "C" void kernel_launch(void* const* d_in, const int* in_sizes, int n_in,
                              void* d_out, int out_size, void* d_ws, size_t ws_size,
                              hipStream_t stream) {
  const float* x    = (const float*)d_in[0];
  const float* ln1g = (const float*)d_in[1];
  const float* ln1b = (const float*)d_in[2];
  const float* Wq   = (const float*)d_in[3];
  const float* Wk   = (const float*)d_in[4];
  const float* Wv   = (const float*)d_in[5];
  const float* Wp   = (const float*)d_in[6];
  const float* bpj  = (const float*)d_in[7];
  const float* ln2g = (const float*)d_in[8];
  const float* ln2b = (const float*)d_in[9];
  const float* W1   = (const float*)d_in[10];
  const float* b1   = (const float*)d_in[11];
  const float* W2   = (const float*)d_in[12];
  const float* b2   = (const float*)d_in[13];
  unsigned short* ws = (unsigned short*)d_ws;
  float* outp = (float*)d_out;

  hipFuncSetAttribute((const void*)mlp_k,
                      hipFuncAttributeMaxDynamicSharedMemorySize, MLP_LDS);

  prep_w<<<3072, 256, 0, stream>>>(Wq, Wk, Wv, Wp, W1, W2, ws);
  attnproj_k<<<4096, 256, 0, stream>>>(x, ln1g, ln1b,
                                       ws, ws + 65536, ws + 131072, ws + 196608,
                                       bpj, outp);
  mlp_k<<<2048, 1024, MLP_LDS, stream>>>(ln2g, ln2b, ws + 262144, b1,
                                         ws + 524288, b2, outp);
}

// Round 16
// 956.572 us; speedup vs baseline: 1.0767x; 1.0767x over previous
//
#include <hip/hip_runtime.h>
#include <hip/hip_bf16.h>

// Fused transformer block as a 3-kernel pipeline:
//   prep_w     : f32 weights -> bf16 transposed in ws (1.5 MB only).
//   attnproj_k : LN1 -> per-head (QKV -> causal softmax -> PV -> proj-accum
//                in regs) -> x2 = x + sa + bproj -> f32 in d_out. Proven R9.
//   mlp_k      : R14 structure (16 waves, 16 out-cols/wave, swapped ops,
//                9 barriers -- proven 478us) + register weight prefetch:
//                w1(ch+1)/w2(ch) loaded into regs BEFORE each barrier so
//                their L2 latency hides under the barrier + phase tail.
//                R14 measured VGPR=52 vs 128 cap -> 64 regs of headroom.
// R15 lesson: mlp is NOT LDS-read-BW-bound (halving reads regressed 43%);
// the per-phase global-load->MFMA serial structure dominates. R14's 1-weight-
// stream / 8-deep-LDS-feed shape is the proven optimum; only hide its load
// latency, change nothing else.
// ws layout (bf16/ushort): [0,65536) WqT[h][d][c]; [65536,131072) WkT;
// [131072,196608) WvT; [196608,262144) WprojT[n][c]; [262144,524288) W1T[n][c];
// [524288,786432) W2T[n][k].  Requires ws_size >= 1572864 bytes only.

typedef float v4f __attribute__((ext_vector_type(4)));
typedef int   v4i __attribute__((ext_vector_type(4)));
typedef float f4v __attribute__((ext_vector_type(4)));
typedef unsigned long long u64;

#define DEV static __device__ __forceinline__

DEV unsigned short f2bf(float f){
  return __builtin_bit_cast(unsigned short, __float2bfloat16(f));
}

// lgkm-only workgroup barrier: orders LDS traffic, leaves global loads in
// flight. Safe because all cross-wave data in these kernels flows via LDS.
DEV void bar(){
  asm volatile("s_waitcnt lgkmcnt(0)\n\ts_barrier" ::: "memory");
}

// bf16 MFMA via inline asm (layout-safe: consistent per-lane contiguous-8 K).
DEV v4f mfma16(v4i a, v4i b, v4f c){
  asm("v_mfma_f32_16x16x32_bf16 %0, %1, %2, %0" : "+v"(c) : "v"(a), "v"(b));
  return c;
}
DEV v4f accfence(v4f c){
  asm("s_nop 7\n\ts_nop 3" : "+v"(c));
  return c;
}

// Swizzled LDS byte offsets (XOR row bits into 16B-granule bits).
DEV int hoff(int r, int c){ return r*512 + ((c*2) ^ ((r & 7) << 4)); }  // [*][256] bf16
DEV int koff(int r, int c){ return r*128 + ((c*2) ^ ((r & 7) << 4)); }  // [*][64]  bf16

DEV u64 pack4(v4f v){
  return (u64)f2bf(v[0]) | ((u64)f2bf(v[1]) << 16)
       | ((u64)f2bf(v[2]) << 32) | ((u64)f2bf(v[3]) << 48);
}

DEV float rsum64(float v){
  #pragma unroll
  for (int k = 1; k < 64; k <<= 1) v += __shfl_xor(v, k);
  return v;
}
DEV float rsum16(float v){
  #pragma unroll
  for (int k = 1; k < 16; k <<= 1) v += __shfl_xor(v, k);
  return v;
}
DEV float rmax16(float v){
  #pragma unroll
  for (int k = 1; k < 16; k <<= 1) v = fmaxf(v, __shfl_xor(v, k));
  return v;
}

__global__ void prep_w(const float* __restrict__ Wq, const float* __restrict__ Wk,
                       const float* __restrict__ Wv, const float* __restrict__ Wp,
                       const float* __restrict__ W1, const float* __restrict__ W2,
                       unsigned short* __restrict__ ws){
  int t = blockIdx.x * 256 + threadIdx.x;   // grid covers exactly 786432
  float v;
  if (t < 196608){
    int seg = t >> 16, r = t & 65535;
    int c = r & 255, d = (r >> 8) & 63, h = r >> 14;
    const float* W = (seg == 0) ? Wq : ((seg == 1) ? Wk : Wv);
    v = W[h*16384 + c*64 + d];
  } else if (t < 262144){
    int r = t - 196608; int n = r >> 8, c = r & 255;
    v = Wp[c*256 + n];
  } else if (t < 524288){
    int r = t - 262144; int n = r >> 8, c = r & 255;
    v = W1[c*1024 + n];
  } else {
    int r = t - 524288; int n = r >> 10, k = r & 1023;
    v = W2[k*256 + n];
  }
  ws[t] = f2bf(v);
}

// ---------------- attnproj_k: LN1 + attention + proj + residual --------------
// One 4-wave block per batch element; proven numerics, unchanged from R9.
__global__ __launch_bounds__(256, 2) void attnproj_k(
    const float* __restrict__ x,
    const float* __restrict__ ln1g, const float* __restrict__ ln1b,
    const unsigned short* __restrict__ wqT,
    const unsigned short* __restrict__ wkT,
    const unsigned short* __restrict__ wvT,
    const unsigned short* __restrict__ wpT,
    const float* __restrict__ bpj,
    float* __restrict__ outp)
{
  __shared__ char smb[65536] __attribute__((aligned(16)));
  char* sm = smb;
  const int HLS = 0, QLS = 32768, KLS = 40960, VTLS = 49152, PATLS = 57344;

  const int b = blockIdx.x;
  const float* __restrict__ xb = x + (size_t)b * 16384;
  float* __restrict__ ob = outp + (size_t)b * 16384;
  const int tid = threadIdx.x;
  const int w = tid >> 6, l = tid & 63, m = l & 15, g = l >> 4;
  const v4f zf = {0.f, 0.f, 0.f, 0.f};

  // Phase A: LN1 -> h (bf16, LDS), 16 rows/wave
  {
    f4v lg = *(const f4v*)(ln1g + 4*l);
    f4v lb = *(const f4v*)(ln1b + 4*l);
    #pragma unroll
    for (int rr = 0; rr < 16; ++rr){
      int r = w*16 + rr;
      f4v xv = *(const f4v*)(xb + r*256 + 4*l);
      float s = xv[0]+xv[1]+xv[2]+xv[3];
      float q = xv[0]*xv[0]+xv[1]*xv[1]+xv[2]*xv[2]+xv[3]*xv[3];
      s = rsum64(s); q = rsum64(q);
      float mu = s * (1.f/256.f);
      float rs = rsqrtf(q * (1.f/256.f) - mu*mu + 1e-6f);
      u64 pk = 0;
      #pragma unroll
      for (int j = 0; j < 4; ++j){
        float hv = (xv[j] - mu) * rs * lg[j] + lb[j];
        pk |= (u64)f2bf(hv) << (16*j);
      }
      *(u64*)(sm + HLS + hoff(r, 4*l)) = pk;
    }
  }
  bar();

  // Phase B: attention; sa accumulated in regs
  v4f sa[4][4];
  #pragma unroll
  for (int i = 0; i < 4; ++i){
    #pragma unroll
    for (int j = 0; j < 4; ++j) sa[i][j] = zf;
  }

  #pragma unroll 1
  for (int hh = 0; hh < 4; ++hh){
    // QKV: wave w owns cols w*16..w*16+15 of q,k,v (shared A-fragments)
    {
      const unsigned short* bq = wqT + hh*16384 + (w*16 + m)*256;
      const unsigned short* bk = wkT + hh*16384 + (w*16 + m)*256;
      const unsigned short* bv = wvT + hh*16384 + (w*16 + m)*256;
      v4f qa[4] = {zf,zf,zf,zf}, ka[4] = {zf,zf,zf,zf}, va[4] = {zf,zf,zf,zf};
      #pragma unroll
      for (int ks = 0; ks < 8; ++ks){
        int k0 = ks*32 + 8*g;
        v4i bq4 = *(const v4i*)(bq + k0);
        v4i bk4 = *(const v4i*)(bk + k0);
        v4i bv4 = *(const v4i*)(bv + k0);
        #pragma unroll
        for (int rt = 0; rt < 4; ++rt){
          v4i af = *(const v4i*)(sm + HLS + hoff(rt*16 + m, k0));
          qa[rt] = mfma16(af, bq4, qa[rt]);
          ka[rt] = mfma16(af, bk4, ka[rt]);
          va[rt] = mfma16(af, bv4, va[rt]);
        }
      }
      #pragma unroll
      for (int rt = 0; rt < 4; ++rt){
        qa[rt] = accfence(qa[rt]); ka[rt] = accfence(ka[rt]); va[rt] = accfence(va[rt]);
        #pragma unroll
        for (int j = 0; j < 4; ++j){
          *(unsigned short*)(sm + QLS + koff(rt*16 + 4*g + j, w*16 + m)) = f2bf(qa[rt][j]);
          *(unsigned short*)(sm + KLS + koff(rt*16 + 4*g + j, w*16 + m)) = f2bf(ka[rt][j]);
        }
        *(u64*)(sm + VTLS + koff(w*16 + m, rt*16 + 4*g)) = pack4(va[rt]);  // V^T
      }
    }
    bar();   // bar1: q,k,v^T ready; prev-head PATLS readers done

    // S = Q K^T (stripe rows w*16..+15) -> softmax -> P -> PV -> own PATLS
    {
      v4f s4[4] = {zf,zf,zf,zf};
      #pragma unroll
      for (int ks = 0; ks < 2; ++ks){
        int k0 = ks*32 + 8*g;
        v4i qf = *(const v4i*)(sm + QLS + koff(w*16 + m, k0));
        #pragma unroll
        for (int nt = 0; nt < 4; ++nt){
          v4i kf = *(const v4i*)(sm + KLS + koff(nt*16 + m, k0));
          s4[nt] = mfma16(qf, kf, s4[nt]);
        }
      }
      #pragma unroll
      for (int nt = 0; nt < 4; ++nt) s4[nt] = accfence(s4[nt]);
      float mx[4] = {-3e38f, -3e38f, -3e38f, -3e38f};
      #pragma unroll
      for (int nt = 0; nt < 4; ++nt){
        #pragma unroll
        for (int j = 0; j < 4; ++j){
          int t = w*16 + 4*g + j, ss = nt*16 + m;
          float z = s4[nt][j] * 0.125f;
          z = (ss <= t) ? z : -1e30f;
          s4[nt][j] = z;
          mx[j] = fmaxf(mx[j], z);
        }
      }
      #pragma unroll
      for (int j = 0; j < 4; ++j) mx[j] = rmax16(mx[j]);
      float sum[4] = {0.f, 0.f, 0.f, 0.f};
      #pragma unroll
      for (int nt = 0; nt < 4; ++nt){
        #pragma unroll
        for (int j = 0; j < 4; ++j){
          float p = __expf(s4[nt][j] - mx[j]);
          s4[nt][j] = p;
          sum[j] += p;
        }
      }
      #pragma unroll
      for (int j = 0; j < 4; ++j) sum[j] = 1.f / rsum16(sum[j]);
      #pragma unroll
      for (int nt = 0; nt < 4; ++nt){
        #pragma unroll
        for (int j = 0; j < 4; ++j)
          *(unsigned short*)(sm + PATLS + w*2048 + koff(4*g + j, nt*16 + m)) =
              f2bf(s4[nt][j] * sum[j]);
      }
      v4f av[4] = {zf,zf,zf,zf};
      #pragma unroll
      for (int ks = 0; ks < 2; ++ks){
        int k0 = ks*32 + 8*g;
        v4i pf = *(const v4i*)(sm + PATLS + w*2048 + koff(m, k0));
        #pragma unroll
        for (int nt = 0; nt < 4; ++nt){
          v4i vf = *(const v4i*)(sm + VTLS + koff(nt*16 + m, k0));
          av[nt] = mfma16(pf, vf, av[nt]);
        }
      }
      #pragma unroll
      for (int nt = 0; nt < 4; ++nt) av[nt] = accfence(av[nt]);
      #pragma unroll
      for (int nt = 0; nt < 4; ++nt){
        #pragma unroll
        for (int j = 0; j < 4; ++j)
          *(unsigned short*)(sm + PATLS + w*2048 + koff(4*g + j, nt*16 + m)) =
              f2bf(av[nt][j]);
      }
    }
    bar();   // bar2: att stripes ready

    // proj: sa += att_head @ Wproj[64*hh:, :]; wave w owns cols w*64..w*64+63
    #pragma unroll
    for (int ks = 0; ks < 2; ++ks){
      int k0 = ks*32 + 8*g;
      v4i af2[4];
      #pragma unroll
      for (int rt = 0; rt < 4; ++rt)
        af2[rt] = *(const v4i*)(sm + PATLS + rt*2048 + koff(m, k0));
      #pragma unroll
      for (int nt = 0; nt < 4; ++nt){
        v4i bp = *(const v4i*)(wpT + (w*64 + nt*16 + m)*256 + hh*64 + k0);
        #pragma unroll
        for (int rt = 0; rt < 4; ++rt) sa[rt][nt] = mfma16(af2[rt], bp, sa[rt][nt]);
      }
    }
    // no trailing barrier: PATLS next written after next bar1.
  }

  // Phase C residual: x2 = x + sa + bproj -> f32 in d_out
  {
    #pragma unroll
    for (int i = 0; i < 4; ++i){
      #pragma unroll
      for (int j = 0; j < 4; ++j) sa[i][j] = accfence(sa[i][j]);
    }
    float bp4[4];
    #pragma unroll
    for (int nt = 0; nt < 4; ++nt) bp4[nt] = bpj[w*64 + nt*16 + m];
    #pragma unroll
    for (int rt = 0; rt < 4; ++rt){
      #pragma unroll
      for (int j = 0; j < 4; ++j){
        int row = rt*16 + 4*g + j;
        #pragma unroll
        for (int nt = 0; nt < 4; ++nt){
          int col = w*64 + nt*16 + m;
          ob[row*256 + col] = xb[row*256 + col] + sa[rt][nt][j] + bp4[nt];
        }
      }
    }
  }
}

// ---------------- mlp_k: 2 batch/block (M=128), 16 waves, reg prefetch ------
// LDS 128KB dynamic: h2 [128][256] bf16 @0 | act chunk [128][256] bf16 @64K.
// 16 waves; wave w owns 16 out-cols per chunk. 4 chunks x (GEMM1, prefetch
// w2(ch)+w1(ch+1), bar, GEMM2, bar) = 9 lgkm barriers (R14 schedule).
// Peak live regs ~ ff(32) + w1r(32) + w2r(32) + temps < 128 cap (R14: 52).
#define MLP_LDS 131072
__global__ __launch_bounds__(1024, 1) void mlp_k(
    const float* __restrict__ ln2g, const float* __restrict__ ln2b,
    const unsigned short* __restrict__ w1T,
    const float* __restrict__ b1,
    const unsigned short* __restrict__ w2T,
    const float* __restrict__ b2,
    float* __restrict__ outp)
{
  extern __shared__ char sm[];
  const int HLS = 0, ACT = 65536;
  const int bb = blockIdx.x;               // 2-batch slab
  float* __restrict__ ob = outp + (size_t)bb * 32768;
  const int tid = threadIdx.x;
  const int w = tid >> 6, l = tid & 63, m = l & 15, g = l >> 4;
  const v4f zf = {0.f, 0.f, 0.f, 0.f};

  // LN2 from x2 (f32 in d_out) -> h2 (bf16, LDS); 16 waves x 8 rows = 128
  {
    f4v lg = *(const f4v*)(ln2g + 4*l);
    f4v lb = *(const f4v*)(ln2b + 4*l);
    #pragma unroll
    for (int rr = 0; rr < 8; ++rr){
      int r = w*8 + rr;
      f4v xv = *(const f4v*)(ob + r*256 + 4*l);
      float s = xv[0]+xv[1]+xv[2]+xv[3];
      float q = xv[0]*xv[0]+xv[1]*xv[1]+xv[2]*xv[2]+xv[3]*xv[3];
      s = rsum64(s); q = rsum64(q);
      float mu = s * (1.f/256.f);
      float rs = rsqrtf(q * (1.f/256.f) - mu*mu + 1e-6f);
      u64 pk = 0;
      #pragma unroll
      for (int j = 0; j < 4; ++j){
        float hv = (xv[j] - mu) * rs * lg[j] + lb[j];
        pk |= (u64)f2bf(hv) << (16*j);
      }
      *(u64*)(sm + HLS + hoff(r, 4*l)) = pk;
    }
  }

  // Preload chunk 0's W1 fragments before the LN2 barrier (latency hidden).
  v4i w1r[8];
  {
    const unsigned short* w1a = w1T + (w*16 + m)*256;   // ch = 0
    #pragma unroll
    for (int ks = 0; ks < 8; ++ks) w1r[ks] = *(const v4i*)(w1a + ks*32 + 8*g);
  }
  bar();

  v4f ff[8];                               // out-cols w*16..+15, 8 row-tiles
  #pragma unroll
  for (int j = 0; j < 8; ++j) ff[j] = zf;

  #pragma unroll 1
  for (int ch = 0; ch < 4; ++ch){
    // GEMM1 (A=W1 from regs, B=h2 rows): a1[rt]
    v4f a1[8];
    #pragma unroll
    for (int j = 0; j < 8; ++j) a1[j] = zf;
    #pragma unroll
    for (int ks = 0; ks < 8; ++ks){
      int k0 = ks*32 + 8*g;
      #pragma unroll
      for (int rt = 0; rt < 8; ++rt){
        v4i bh = *(const v4i*)(sm + HLS + hoff(rt*16 + m, k0));
        a1[rt] = mfma16(w1r[ks], bh, a1[rt]);
      }
    }
    // bias + relu + packed act store: act[row = rt*16+m][col = w*16+4g+j]
    f4v b1f = *(const f4v*)(b1 + ch*256 + w*16 + 4*g);
    #pragma unroll
    for (int j = 0; j < 8; ++j) a1[j] = accfence(a1[j]);
    #pragma unroll
    for (int rt = 0; rt < 8; ++rt){
      v4f v;
      #pragma unroll
      for (int j = 0; j < 4; ++j) v[j] = fmaxf(a1[rt][j] + b1f[j], 0.f);
      *(u64*)(sm + ACT + hoff(rt*16 + m, w*16 + 4*g)) = pack4(v);
    }

    // Prefetch W2(ch) + W1(ch+1) into regs BEFORE the barrier: their L2
    // latency hides under the barrier and GEMM2's LDS-read phase.
    v4i w2r[8];
    {
      const unsigned short* w2a = w2T + (w*16 + m)*1024 + ch*256;
      #pragma unroll
      for (int ks = 0; ks < 8; ++ks) w2r[ks] = *(const v4i*)(w2a + ks*32 + 8*g);
    }
    if (ch < 3){
      const unsigned short* w1a = w1T + ((ch+1)*256 + w*16 + m)*256;
      #pragma unroll
      for (int ks = 0; ks < 8; ++ks) w1r[ks] = *(const v4i*)(w1a + ks*32 + 8*g);
    }
    bar();   // act chunk ready

    // GEMM2 (A=W2 from regs, B=act rows): ff[rt]
    #pragma unroll
    for (int ks = 0; ks < 8; ++ks){
      int k0 = ks*32 + 8*g;
      #pragma unroll
      for (int rt = 0; rt < 8; ++rt){
        v4i bact = *(const v4i*)(sm + ACT + hoff(rt*16 + m, k0));
        ff[rt] = mfma16(w2r[ks], bact, ff[rt]);
      }
    }
    bar();   // protect act before next chunk's GEMM1 overwrite
  }

  // Final: out = x2 + ff + b2, float4 RMW (4 consecutive cols per lane)
  {
    f4v b2f = *(const f4v*)(b2 + w*16 + 4*g);
    #pragma unroll
    for (int j = 0; j < 8; ++j) ff[j] = accfence(ff[j]);
    #pragma unroll
    for (int rt = 0; rt < 8; ++rt){
      int row = rt*16 + m;
      f4v* p = (f4v*)(ob + row*256 + w*16 + 4*g);
      f4v v = *p;
      #pragma unroll
      for (int j = 0; j < 4; ++j) v[j] += ff[rt][j] + b2f[j];
      *p = v;
    }
  }
}

extern "C" void kernel_launch(void* const* d_in, const int* in_sizes, int n_in,
                              void* d_out, int out_size, void* d_ws, size_t ws_size,
                              hipStream_t stream) {
  const float* x    = (const float*)d_in[0];
  const float* ln1g = (const float*)d_in[1];
  const float* ln1b = (const float*)d_in[2];
  const float* Wq   = (const float*)d_in[3];
  const float* Wk   = (const float*)d_in[4];
  const float* Wv   = (const float*)d_in[5];
  const float* Wp   = (const float*)d_in[6];
  const float* bpj  = (const float*)d_in[7];
  const float* ln2g = (const float*)d_in[8];
  const float* ln2b = (const float*)d_in[9];
  const float* W1   = (const float*)d_in[10];
  const float* b1   = (const float*)d_in[11];
  const float* W2   = (const float*)d_in[12];
  const float* b2   = (const float*)d_in[13];
  unsigned short* ws = (unsigned short*)d_ws;
  float* outp = (float*)d_out;

  hipFuncSetAttribute((const void*)mlp_k,
                      hipFuncAttributeMaxDynamicSharedMemorySize, MLP_LDS);

  prep_w<<<3072, 256, 0, stream>>>(Wq, Wk, Wv, Wp, W1, W2, ws);
  attnproj_k<<<4096, 256, 0, stream>>>(x, ln1g, ln1b,
                                       ws, ws + 65536, ws + 131072, ws + 196608,
                                       bpj, outp);
  mlp_k<<<2048, 1024, MLP_LDS, stream>>>(ln2g, ln2b, ws + 262144, b1,
                                         ws + 524288, b2, outp);
}

// Round 19
// 821.453 us; speedup vs baseline: 1.2538x; 1.1645x over previous
//
#include <hip/hip_runtime.h>
#include <hip/hip_bf16.h>

// Fused transformer block as a 3-kernel pipeline (best proven config, R14):
//   prep_w     : f32 weights -> bf16 transposed in ws (1.5 MB only).
//   attnproj_k : 4-wave/block per batch element: LN1 -> per-head (QKV ->
//                causal softmax -> PV -> proj-accum in regs) -> x2 -> d_out.
//   mlp_k      : 16 waves, 2 batch/block, swapped-operand GEMMs (A=weights ->
//                packed ds_write_b64 act stores + float4 residual RMW).
// Lessons locked in: (R12/R16) manual reg-prefetch spills or defeats the
// compiler's pipelining; (R15) narrowing LDS feeds regresses; (R17/R18) the
// 8-wave attn reconstruction fails correctness -> reverted to green.
// ws layout (bf16/ushort): [0,65536) WqT[h][d][c]; [65536,131072) WkT;
// [131072,196608) WvT; [196608,262144) WprojT[n][c]; [262144,524288) W1T[n][c];
// [524288,786432) W2T[n][k].  Requires ws_size >= 1572864 bytes only.

typedef float v4f __attribute__((ext_vector_type(4)));
typedef int   v4i __attribute__((ext_vector_type(4)));
typedef float f4v __attribute__((ext_vector_type(4)));
typedef unsigned long long u64;

#define DEV static __device__ __forceinline__

DEV unsigned short f2bf(float f){
  return __builtin_bit_cast(unsigned short, __float2bfloat16(f));
}

// lgkm-only workgroup barrier: orders LDS traffic, leaves global loads in
// flight. Proven safe in uniform-role kernels only.
DEV void bar(){
  asm volatile("s_waitcnt lgkmcnt(0)\n\ts_barrier" ::: "memory");
}

// bf16 MFMA via inline asm (layout-safe: consistent per-lane contiguous-8 K).
DEV v4f mfma16(v4i a, v4i b, v4f c){
  asm("v_mfma_f32_16x16x32_bf16 %0, %1, %2, %0" : "+v"(c) : "v"(a), "v"(b));
  return c;
}
DEV v4f accfence(v4f c){
  asm("s_nop 7\n\ts_nop 3" : "+v"(c));
  return c;
}

// Swizzled LDS byte offsets (XOR row bits into 16B-granule bits).
DEV int hoff(int r, int c){ return r*512 + ((c*2) ^ ((r & 7) << 4)); }  // [*][256] bf16
DEV int koff(int r, int c){ return r*128 + ((c*2) ^ ((r & 7) << 4)); }  // [*][64]  bf16

DEV u64 pack4(v4f v){
  return (u64)f2bf(v[0]) | ((u64)f2bf(v[1]) << 16)
       | ((u64)f2bf(v[2]) << 32) | ((u64)f2bf(v[3]) << 48);
}

DEV float rsum64(float v){
  #pragma unroll
  for (int k = 1; k < 64; k <<= 1) v += __shfl_xor(v, k);
  return v;
}
DEV float rsum16(float v){
  #pragma unroll
  for (int k = 1; k < 16; k <<= 1) v += __shfl_xor(v, k);
  return v;
}
DEV float rmax16(float v){
  #pragma unroll
  for (int k = 1; k < 16; k <<= 1) v = fmaxf(v, __shfl_xor(v, k));
  return v;
}

__global__ void prep_w(const float* __restrict__ Wq, const float* __restrict__ Wk,
                       const float* __restrict__ Wv, const float* __restrict__ Wp,
                       const float* __restrict__ W1, const float* __restrict__ W2,
                       unsigned short* __restrict__ ws){
  int t = blockIdx.x * 256 + threadIdx.x;   // grid covers exactly 786432
  float v;
  if (t < 196608){
    int seg = t >> 16, r = t & 65535;
    int c = r & 255, d = (r >> 8) & 63, h = r >> 14;
    const float* W = (seg == 0) ? Wq : ((seg == 1) ? Wk : Wv);
    v = W[h*16384 + c*64 + d];
  } else if (t < 262144){
    int r = t - 196608; int n = r >> 8, c = r & 255;
    v = Wp[c*256 + n];
  } else if (t < 524288){
    int r = t - 262144; int n = r >> 8, c = r & 255;
    v = W1[c*1024 + n];
  } else {
    int r = t - 524288; int n = r >> 10, k = r & 1023;
    v = W2[k*256 + n];
  }
  ws[t] = f2bf(v);
}

// ---------------- attnproj_k: LN1 + attention + proj + residual --------------
// One 4-wave block per batch element; proven numerics (R9-R16 lineage).
__global__ __launch_bounds__(256, 2) void attnproj_k(
    const float* __restrict__ x,
    const float* __restrict__ ln1g, const float* __restrict__ ln1b,
    const unsigned short* __restrict__ wqT,
    const unsigned short* __restrict__ wkT,
    const unsigned short* __restrict__ wvT,
    const unsigned short* __restrict__ wpT,
    const float* __restrict__ bpj,
    float* __restrict__ outp)
{
  __shared__ char smb[65536] __attribute__((aligned(16)));
  char* sm = smb;
  const int HLS = 0, QLS = 32768, KLS = 40960, VTLS = 49152, PATLS = 57344;

  const int b = blockIdx.x;
  const float* __restrict__ xb = x + (size_t)b * 16384;
  float* __restrict__ ob = outp + (size_t)b * 16384;
  const int tid = threadIdx.x;
  const int w = tid >> 6, l = tid & 63, m = l & 15, g = l >> 4;
  const v4f zf = {0.f, 0.f, 0.f, 0.f};

  // Phase A: LN1 -> h (bf16, LDS), 16 rows/wave
  {
    f4v lg = *(const f4v*)(ln1g + 4*l);
    f4v lb = *(const f4v*)(ln1b + 4*l);
    #pragma unroll
    for (int rr = 0; rr < 16; ++rr){
      int r = w*16 + rr;
      f4v xv = *(const f4v*)(xb + r*256 + 4*l);
      float s = xv[0]+xv[1]+xv[2]+xv[3];
      float q = xv[0]*xv[0]+xv[1]*xv[1]+xv[2]*xv[2]+xv[3]*xv[3];
      s = rsum64(s); q = rsum64(q);
      float mu = s * (1.f/256.f);
      float rs = rsqrtf(q * (1.f/256.f) - mu*mu + 1e-6f);
      u64 pk = 0;
      #pragma unroll
      for (int j = 0; j < 4; ++j){
        float hv = (xv[j] - mu) * rs * lg[j] + lb[j];
        pk |= (u64)f2bf(hv) << (16*j);
      }
      *(u64*)(sm + HLS + hoff(r, 4*l)) = pk;
    }
  }
  bar();

  // Phase B: attention; sa accumulated in regs
  v4f sa[4][4];
  #pragma unroll
  for (int i = 0; i < 4; ++i){
    #pragma unroll
    for (int j = 0; j < 4; ++j) sa[i][j] = zf;
  }

  #pragma unroll 1
  for (int hh = 0; hh < 4; ++hh){
    // QKV: wave w owns cols w*16..w*16+15 of q,k,v (shared A-fragments)
    {
      const unsigned short* bq = wqT + hh*16384 + (w*16 + m)*256;
      const unsigned short* bk = wkT + hh*16384 + (w*16 + m)*256;
      const unsigned short* bv = wvT + hh*16384 + (w*16 + m)*256;
      v4f qa[4] = {zf,zf,zf,zf}, ka[4] = {zf,zf,zf,zf}, va[4] = {zf,zf,zf,zf};
      #pragma unroll
      for (int ks = 0; ks < 8; ++ks){
        int k0 = ks*32 + 8*g;
        v4i bq4 = *(const v4i*)(bq + k0);
        v4i bk4 = *(const v4i*)(bk + k0);
        v4i bv4 = *(const v4i*)(bv + k0);
        #pragma unroll
        for (int rt = 0; rt < 4; ++rt){
          v4i af = *(const v4i*)(sm + HLS + hoff(rt*16 + m, k0));
          qa[rt] = mfma16(af, bq4, qa[rt]);
          ka[rt] = mfma16(af, bk4, ka[rt]);
          va[rt] = mfma16(af, bv4, va[rt]);
        }
      }
      #pragma unroll
      for (int rt = 0; rt < 4; ++rt){
        qa[rt] = accfence(qa[rt]); ka[rt] = accfence(ka[rt]); va[rt] = accfence(va[rt]);
        #pragma unroll
        for (int j = 0; j < 4; ++j){
          *(unsigned short*)(sm + QLS + koff(rt*16 + 4*g + j, w*16 + m)) = f2bf(qa[rt][j]);
          *(unsigned short*)(sm + KLS + koff(rt*16 + 4*g + j, w*16 + m)) = f2bf(ka[rt][j]);
        }
        *(u64*)(sm + VTLS + koff(w*16 + m, rt*16 + 4*g)) = pack4(va[rt]);  // V^T
      }
    }
    bar();   // bar1: q,k,v^T ready; prev-head PATLS readers done

    // S = Q K^T (stripe rows w*16..+15) -> softmax -> P -> PV -> own PATLS
    {
      v4f s4[4] = {zf,zf,zf,zf};
      #pragma unroll
      for (int ks = 0; ks < 2; ++ks){
        int k0 = ks*32 + 8*g;
        v4i qf = *(const v4i*)(sm + QLS + koff(w*16 + m, k0));
        #pragma unroll
        for (int nt = 0; nt < 4; ++nt){
          v4i kf = *(const v4i*)(sm + KLS + koff(nt*16 + m, k0));
          s4[nt] = mfma16(qf, kf, s4[nt]);
        }
      }
      #pragma unroll
      for (int nt = 0; nt < 4; ++nt) s4[nt] = accfence(s4[nt]);
      float mx[4] = {-3e38f, -3e38f, -3e38f, -3e38f};
      #pragma unroll
      for (int nt = 0; nt < 4; ++nt){
        #pragma unroll
        for (int j = 0; j < 4; ++j){
          int t = w*16 + 4*g + j, ss = nt*16 + m;
          float z = s4[nt][j] * 0.125f;
          z = (ss <= t) ? z : -1e30f;
          s4[nt][j] = z;
          mx[j] = fmaxf(mx[j], z);
        }
      }
      #pragma unroll
      for (int j = 0; j < 4; ++j) mx[j] = rmax16(mx[j]);
      float sum[4] = {0.f, 0.f, 0.f, 0.f};
      #pragma unroll
      for (int nt = 0; nt < 4; ++nt){
        #pragma unroll
        for (int j = 0; j < 4; ++j){
          float p = __expf(s4[nt][j] - mx[j]);
          s4[nt][j] = p;
          sum[j] += p;
        }
      }
      #pragma unroll
      for (int j = 0; j < 4; ++j) sum[j] = 1.f / rsum16(sum[j]);
      #pragma unroll
      for (int nt = 0; nt < 4; ++nt){
        #pragma unroll
        for (int j = 0; j < 4; ++j)
          *(unsigned short*)(sm + PATLS + w*2048 + koff(4*g + j, nt*16 + m)) =
              f2bf(s4[nt][j] * sum[j]);
      }
      v4f av[4] = {zf,zf,zf,zf};
      #pragma unroll
      for (int ks = 0; ks < 2; ++ks){
        int k0 = ks*32 + 8*g;
        v4i pf = *(const v4i*)(sm + PATLS + w*2048 + koff(m, k0));
        #pragma unroll
        for (int nt = 0; nt < 4; ++nt){
          v4i vf = *(const v4i*)(sm + VTLS + koff(nt*16 + m, k0));
          av[nt] = mfma16(pf, vf, av[nt]);
        }
      }
      #pragma unroll
      for (int nt = 0; nt < 4; ++nt) av[nt] = accfence(av[nt]);
      #pragma unroll
      for (int nt = 0; nt < 4; ++nt){
        #pragma unroll
        for (int j = 0; j < 4; ++j)
          *(unsigned short*)(sm + PATLS + w*2048 + koff(4*g + j, nt*16 + m)) =
              f2bf(av[nt][j]);
      }
    }
    bar();   // bar2: att stripes ready

    // proj: sa += att_head @ Wproj[64*hh:, :]; wave w owns cols w*64..w*64+63
    #pragma unroll
    for (int ks = 0; ks < 2; ++ks){
      int k0 = ks*32 + 8*g;
      v4i af2[4];
      #pragma unroll
      for (int rt = 0; rt < 4; ++rt)
        af2[rt] = *(const v4i*)(sm + PATLS + rt*2048 + koff(m, k0));
      #pragma unroll
      for (int nt = 0; nt < 4; ++nt){
        v4i bp = *(const v4i*)(wpT + (w*64 + nt*16 + m)*256 + hh*64 + k0);
        #pragma unroll
        for (int rt = 0; rt < 4; ++rt) sa[rt][nt] = mfma16(af2[rt], bp, sa[rt][nt]);
      }
    }
    // no trailing barrier: PATLS next written after next bar1.
  }

  // Phase C residual: x2 = x + sa + bproj -> f32 in d_out
  {
    #pragma unroll
    for (int i = 0; i < 4; ++i){
      #pragma unroll
      for (int j = 0; j < 4; ++j) sa[i][j] = accfence(sa[i][j]);
    }
    float bp4[4];
    #pragma unroll
    for (int nt = 0; nt < 4; ++nt) bp4[nt] = bpj[w*64 + nt*16 + m];
    #pragma unroll
    for (int rt = 0; rt < 4; ++rt){
      #pragma unroll
      for (int j = 0; j < 4; ++j){
        int row = rt*16 + 4*g + j;
        #pragma unroll
        for (int nt = 0; nt < 4; ++nt){
          int col = w*64 + nt*16 + m;
          ob[row*256 + col] = xb[row*256 + col] + sa[rt][nt][j] + bp4[nt];
        }
      }
    }
  }
}

// ---------------- mlp_k: 2 batch/block (M=128), 16 waves, swapped ops --------
// LDS 128KB dynamic: h2 [128][256] bf16 @0 | act chunk [128][256] bf16 @64K.
// 16 waves; wave w owns 16 out-cols per chunk. 4 chunks x (GEMM1, bar,
// GEMM2, bar) = 9 lgkm barriers. A=weights -> packed u64 act stores and
// float4 residual RMW. Proven 478us, VGPR=52.
#define MLP_LDS 131072
__global__ __launch_bounds__(1024, 1) void mlp_k(
    const float* __restrict__ ln2g, const float* __restrict__ ln2b,
    const unsigned short* __restrict__ w1T,
    const float* __restrict__ b1,
    const unsigned short* __restrict__ w2T,
    const float* __restrict__ b2,
    float* __restrict__ outp)
{
  extern __shared__ char sm[];
  const int HLS = 0, ACT = 65536;
  const int bb = blockIdx.x;               // 2-batch slab
  float* __restrict__ ob = outp + (size_t)bb * 32768;
  const int tid = threadIdx.x;
  const int w = tid >> 6, l = tid & 63, m = l & 15, g = l >> 4;
  const v4f zf = {0.f, 0.f, 0.f, 0.f};

  // LN2 from x2 (f32 in d_out) -> h2 (bf16, LDS); 16 waves x 8 rows = 128
  {
    f4v lg = *(const f4v*)(ln2g + 4*l);
    f4v lb = *(const f4v*)(ln2b + 4*l);
    #pragma unroll
    for (int rr = 0; rr < 8; ++rr){
      int r = w*8 + rr;
      f4v xv = *(const f4v*)(ob + r*256 + 4*l);
      float s = xv[0]+xv[1]+xv[2]+xv[3];
      float q = xv[0]*xv[0]+xv[1]*xv[1]+xv[2]*xv[2]+xv[3]*xv[3];
      s = rsum64(s); q = rsum64(q);
      float mu = s * (1.f/256.f);
      float rs = rsqrtf(q * (1.f/256.f) - mu*mu + 1e-6f);
      u64 pk = 0;
      #pragma unroll
      for (int j = 0; j < 4; ++j){
        float hv = (xv[j] - mu) * rs * lg[j] + lb[j];
        pk |= (u64)f2bf(hv) << (16*j);
      }
      *(u64*)(sm + HLS + hoff(r, 4*l)) = pk;
    }
  }
  bar();

  v4f ff[8];                               // out-cols w*16..+15, 8 row-tiles
  #pragma unroll
  for (int j = 0; j < 8; ++j) ff[j] = zf;

  #pragma unroll 1
  for (int ch = 0; ch < 4; ++ch){
    // GEMM1 (A=W1T rows = out-cols, B=h2 rows): a1[rt]
    v4f a1[8];
    #pragma unroll
    for (int j = 0; j < 8; ++j) a1[j] = zf;
    const unsigned short* w1a = w1T + (ch*256 + w*16 + m)*256;
    #pragma unroll
    for (int ks = 0; ks < 8; ++ks){
      int k0 = ks*32 + 8*g;
      v4i aw0 = *(const v4i*)(w1a + k0);
      #pragma unroll
      for (int rt = 0; rt < 8; ++rt){
        v4i bh = *(const v4i*)(sm + HLS + hoff(rt*16 + m, k0));
        a1[rt] = mfma16(aw0, bh, a1[rt]);
      }
    }
    // bias + relu + packed act store: act[row = rt*16+m][col = w*16+4g+j]
    f4v b1f = *(const f4v*)(b1 + ch*256 + w*16 + 4*g);
    #pragma unroll
    for (int j = 0; j < 8; ++j) a1[j] = accfence(a1[j]);
    #pragma unroll
    for (int rt = 0; rt < 8; ++rt){
      v4f v;
      #pragma unroll
      for (int j = 0; j < 4; ++j) v[j] = fmaxf(a1[rt][j] + b1f[j], 0.f);
      *(u64*)(sm + ACT + hoff(rt*16 + m, w*16 + 4*g)) = pack4(v);
    }
    bar();   // act chunk ready

    // GEMM2 (A=W2T rows = final out-cols, B=act rows): ff[rt]
    const unsigned short* w2a = w2T + (w*16 + m)*1024 + ch*256;
    #pragma unroll
    for (int ks = 0; ks < 8; ++ks){
      int k0 = ks*32 + 8*g;
      v4i aw0 = *(const v4i*)(w2a + k0);
      #pragma unroll
      for (int rt = 0; rt < 8; ++rt){
        v4i bact = *(const v4i*)(sm + ACT + hoff(rt*16 + m, k0));
        ff[rt] = mfma16(aw0, bact, ff[rt]);
      }
    }
    bar();   // protect act before next chunk's GEMM1 overwrite
  }

  // Final: out = x2 + ff + b2, float4 RMW (4 consecutive cols per lane)
  {
    f4v b2f = *(const f4v*)(b2 + w*16 + 4*g);
    #pragma unroll
    for (int j = 0; j < 8; ++j) ff[j] = accfence(ff[j]);
    #pragma unroll
    for (int rt = 0; rt < 8; ++rt){
      int row = rt*16 + m;
      f4v* p = (f4v*)(ob + row*256 + w*16 + 4*g);
      f4v v = *p;
      #pragma unroll
      for (int j = 0; j < 4; ++j) v[j] += ff[rt][j] + b2f[j];
      *p = v;
    }
  }
}

extern "C" void kernel_launch(void* const* d_in, const int* in_sizes, int n_in,
                              void* d_out, int out_size, void* d_ws, size_t ws_size,
                              hipStream_t stream) {
  const float* x    = (const float*)d_in[0];
  const float* ln1g = (const float*)d_in[1];
  const float* ln1b = (const float*)d_in[2];
  const float* Wq   = (const float*)d_in[3];
  const float* Wk   = (const float*)d_in[4];
  const float* Wv   = (const float*)d_in[5];
  const float* Wp   = (const float*)d_in[6];
  const float* bpj  = (const float*)d_in[7];
  const float* ln2g = (const float*)d_in[8];
  const float* ln2b = (const float*)d_in[9];
  const float* W1   = (const float*)d_in[10];
  const float* b1   = (const float*)d_in[11];
  const float* W2   = (const float*)d_in[12];
  const float* b2   = (const float*)d_in[13];
  unsigned short* ws = (unsigned short*)d_ws;
  float* outp = (float*)d_out;

  hipFuncSetAttribute((const void*)mlp_k,
                      hipFuncAttributeMaxDynamicSharedMemorySize, MLP_LDS);

  prep_w<<<3072, 256, 0, stream>>>(Wq, Wk, Wv, Wp, W1, W2, ws);
  attnproj_k<<<4096, 256, 0, stream>>>(x, ln1g, ln1b,
                                       ws, ws + 65536, ws + 131072, ws + 196608,
                                       bpj, outp);
  mlp_k<<<2048, 1024, MLP_LDS, stream>>>(ln2g, ln2b, ws + 262144, b1,
                                         ws + 524288, b2, outp);
}